// Round 1
// baseline (18137.265 us; speedup 1.0000x reference)
//
#include <hip/hip_runtime.h>

// ---------------------------------------------------------------------------
// LSTM recurrence, T=2048, B=32, D=H=512.
//   Phase 1: xp = input @ W_x + b   (bf16 MFMA GEMM, 65536x512x2048) -> ws (bf16)
//   Phase 2: persistent 32-WG recurrence kernel, W_h register-resident as
//            pre-swizzled MFMA B-fragments, m double-buffered in global memory
//            in MFMA A-fragment layout, fp32 c/m state in registers.
// ---------------------------------------------------------------------------

typedef __bf16  bf16x8 __attribute__((ext_vector_type(8)));
typedef float   f32x4  __attribute__((ext_vector_type(4)));

__device__ __forceinline__ unsigned short f2bf(float f) {
  unsigned u = __builtin_bit_cast(unsigned, f);
  u += 0x7fffu + ((u >> 16) & 1u);   // round-to-nearest-even
  return (unsigned short)(u >> 16);
}
__device__ __forceinline__ float bf2f(unsigned short h) {
  unsigned u = ((unsigned)h) << 16;
  return __builtin_bit_cast(float, u);
}
__device__ __forceinline__ float fast_sigmoid(float x) {
  return 1.0f / (1.0f + __expf(-x));
}
__device__ __forceinline__ float fast_tanh(float x) {
  return 2.0f / (1.0f + __expf(-2.0f * x)) - 1.0f;
}

// ---------------------------------------------------------------------------
// Transpose + fp32->bf16 convert: W [512][2048] -> WT [2048][512] bf16.
// blockIdx.z: 0 = W_x, 1 = W_h.
// ---------------------------------------------------------------------------
__global__ __launch_bounds__(256) void transpose_cvt(
    const float* __restrict__ Wx, const float* __restrict__ Wh,
    unsigned short* __restrict__ WxT, unsigned short* __restrict__ WhT) {
  const float* src = blockIdx.z ? Wh : Wx;
  unsigned short* dst = blockIdx.z ? WhT : WxT;
  __shared__ float tile[32][33];
  const int n0 = blockIdx.x * 32, k0 = blockIdx.y * 32;
  const int t = threadIdx.x;
  {
    const int kk = t >> 3, nn = (t & 7) * 4;
    float4 v = *(const float4*)(src + (size_t)(k0 + kk) * 2048 + n0 + nn);
    tile[kk][nn + 0] = v.x; tile[kk][nn + 1] = v.y;
    tile[kk][nn + 2] = v.z; tile[kk][nn + 3] = v.w;
  }
  __syncthreads();
  {
    const int n = t >> 3, k4 = (t & 7) * 4;
    ushort4 o;
    o.x = f2bf(tile[k4 + 0][n]); o.y = f2bf(tile[k4 + 1][n]);
    o.z = f2bf(tile[k4 + 2][n]); o.w = f2bf(tile[k4 + 3][n]);
    *(ushort4*)(dst + (size_t)(n0 + n) * 512 + k0 + k4) = o;
  }
}

// ---------------------------------------------------------------------------
// xp = input @ W_x + b, output bf16 [65536][2048].
// 128x128 tile per 256-thread WG, 4 waves in 2x2, 16x16x32 bf16 MFMA.
// A = input fp32 [65536][512] (convert during staging), B = WxT bf16 [2048][512].
// ---------------------------------------------------------------------------
__global__ __launch_bounds__(256) void gemm_xproj(
    const float* __restrict__ A, const unsigned short* __restrict__ BT,
    const float* __restrict__ bias, unsigned short* __restrict__ C) {
  __shared__ unsigned short As[128 * 32];  // [row][k] bf16
  __shared__ unsigned short Bs[128 * 32];  // [n][k]   bf16
  const int m0 = blockIdx.x * 128, n0 = blockIdx.y * 128;
  const int tid = threadIdx.x, w = tid >> 6, lane = tid & 63;
  const int q = lane >> 4, r = lane & 15;
  const int wm = (w >> 1) * 64, wn = (w & 1) * 64;
  const int srow = tid >> 1, shalf = tid & 1;

  f32x4 acc[4][4] = {};

  for (int kt = 0; kt < 16; ++kt) {
    const int k0 = kt * 32;
    // stage A (fp32 -> bf16): 16 floats per thread
    {
      const float* ap = A + (size_t)(m0 + srow) * 512 + k0 + shalf * 16;
#pragma unroll
      for (int c = 0; c < 4; ++c) {
        float4 v = *(const float4*)(ap + c * 4);
        ushort4 h;
        h.x = f2bf(v.x); h.y = f2bf(v.y); h.z = f2bf(v.z); h.w = f2bf(v.w);
        *(ushort4*)&As[srow * 32 + shalf * 16 + c * 4] = h;
      }
    }
    // stage B (already bf16, [n][k] rows contiguous): 16 bf16 per thread
    {
      const unsigned short* bp = BT + (size_t)(n0 + srow) * 512 + k0 + shalf * 16;
#pragma unroll
      for (int c2 = 0; c2 < 2; ++c2)
        *(uint4*)&Bs[srow * 32 + shalf * 16 + c2 * 8] = *(const uint4*)(bp + c2 * 8);
    }
    __syncthreads();
    bf16x8 af[4], bfr[4];
#pragma unroll
    for (int i = 0; i < 4; ++i)
      af[i] = *(const bf16x8*)&As[(wm + i * 16 + r) * 32 + q * 8];
#pragma unroll
    for (int j = 0; j < 4; ++j)
      bfr[j] = *(const bf16x8*)&Bs[(wn + j * 16 + r) * 32 + q * 8];
#pragma unroll
    for (int i = 0; i < 4; ++i)
#pragma unroll
      for (int j = 0; j < 4; ++j)
        acc[i][j] = __builtin_amdgcn_mfma_f32_16x16x32_bf16(af[i], bfr[j], acc[i][j], 0, 0, 0);
    __syncthreads();
  }
  // epilogue: D row = (lane>>4)*4 + e, col = lane&15  (m89-verified layout)
#pragma unroll
  for (int j = 0; j < 4; ++j) {
    const int col = n0 + wn + j * 16 + r;
    const float bv = bias[col];
#pragma unroll
    for (int i = 0; i < 4; ++i) {
#pragma unroll
      for (int e = 0; e < 4; ++e) {
        const int row = m0 + wm + i * 16 + q * 4 + e;
        C[(size_t)row * 2048 + col] = f2bf(acc[i][j][e] + bv);
      }
    }
  }
}

// ---------------------------------------------------------------------------
// Persistent recurrence kernel: 32 WGs x 256 threads.
// WG g owns h in [g*16, g*16+16)  -> 64 gate columns {type*512 + h}.
// Wave w owns n_loc in [w*16, w*16+16), n_loc = h_loc*4 + type (mixed tile).
// m buffers (global, bf16) are stored in MFMA-A-fragment-swizzled layout:
//   element (row,k):  byte = ((k>>5)*2 + (row>>4))*1024 + (((k>>3)&3)*16 + (row&15))*16 + (k&7)*2
// ---------------------------------------------------------------------------
__global__ __launch_bounds__(256, 1) void lstm_rec(
    const unsigned short* __restrict__ xp,   // [65536][2048] bf16
    const float* __restrict__ pads,          // [2048*32]
    const unsigned short* __restrict__ WhT,  // [2048][512] bf16
    float* __restrict__ out,                 // [T*B*H + 2*B*H] fp32
    unsigned short* __restrict__ mb0, unsigned short* __restrict__ mb1,
    unsigned int* __restrict__ ctr) {
  const int g = blockIdx.x, tid = threadIdx.x;
  const int w = tid >> 6, lane = tid & 63, q = lane >> 4, r = lane & 15;

  __shared__ unsigned short mA[32 * 512];  // 32 KB, swizzled m copy
  __shared__ float gsm[32 * 64];           // gates [row][n_loc] fp32, 8 KB

  // ---- register-resident W_h B-fragments ----
  const int n_loc = w * 16 + r;
  const int h_loc = n_loc >> 2, typ = n_loc & 3;
  const int n_glob = typ * 512 + g * 16 + h_loc;
  bf16x8 bfrag[16];
#pragma unroll
  for (int kt = 0; kt < 16; ++kt)
    bfrag[kt] = *(const bf16x8*)(WhT + (size_t)n_glob * 512 + kt * 32 + q * 8);

  // ---- elementwise cell ownership (threads 0..63): 8 cells each ----
  const int mt = (tid >> 5) & 1, qh = (tid >> 4) & 1, rr = tid & 15;
  const int srow = mt * 16 + rr;          // batch row
  const int hbase = g * 16 + qh * 8;      // global h of j=0
  const int blk = 2 * g + qh;             // = h>>3
  const size_t mwoff = (size_t)((blk >> 2) * 2 + mt) * 1024 +
                       (size_t)((blk & 3) * 16 + rr) * 16;  // byte offset in m buffer
  float cst[8], mst[8];
#pragma unroll
  for (int j = 0; j < 8; ++j) { cst[j] = 0.f; mst[j] = 0.f; }

  for (int t = 0; t < 2048; ++t) {
    const unsigned short* mr = (t & 1) ? mb1 : mb0;
    unsigned short* mw = (t & 1) ? mb0 : mb1;

    // stage m (flat 32 KB copy, already fragment-swizzled)
#pragma unroll
    for (int i = 0; i < 8; ++i)
      *(uint4*)((char*)mA + tid * 16 + i * 4096) =
          *(const uint4*)((const char*)mr + tid * 16 + i * 4096);
    __syncthreads();

    // GEMM: gates slice = m @ W_h[:, slice]
    f32x4 acc0 = {}, acc1 = {};
#pragma unroll
    for (int kt = 0; kt < 16; ++kt) {
      bf16x8 a0 = *(const bf16x8*)((const char*)mA + (size_t)(kt * 2 + 0) * 1024 + lane * 16);
      bf16x8 a1 = *(const bf16x8*)((const char*)mA + (size_t)(kt * 2 + 1) * 1024 + lane * 16);
      acc0 = __builtin_amdgcn_mfma_f32_16x16x32_bf16(a0, bfrag[kt], acc0, 0, 0, 0);
      acc1 = __builtin_amdgcn_mfma_f32_16x16x32_bf16(a1, bfrag[kt], acc1, 0, 0, 0);
    }
#pragma unroll
    for (int e = 0; e < 4; ++e) {
      gsm[(q * 4 + e) * 64 + n_loc] = acc0[e];        // rows 0..15
      gsm[(16 + q * 4 + e) * 64 + n_loc] = acc1[e];   // rows 16..31
    }
    __syncthreads();

    // elementwise LSTM cell (wave 0 only)
    if (tid < 64) {
      const float p = pads[t * 32 + srow];
      const unsigned short* xr = xp + (size_t)(t * 32 + srow) * 2048 + hbase;
      uint4 xu[4];
#pragma unroll
      for (int ty = 0; ty < 4; ++ty) xu[ty] = *(const uint4*)(xr + ty * 512);
      const unsigned short* xs = (const unsigned short*)xu;
      const float* gr = &gsm[srow * 64 + qh * 32];
      float m2a[8];
      union { unsigned short s[8]; uint4 u; } mwp;
#pragma unroll
      for (int j = 0; j < 8; ++j) {
        const float iv = gr[j * 4 + 0] + bf2f(xs[j]);
        const float fv = gr[j * 4 + 1] + bf2f(xs[8 + j]);
        const float gv = gr[j * 4 + 2] + bf2f(xs[16 + j]);
        const float ov = gr[j * 4 + 3] + bf2f(xs[24 + j]);
        const float si = fast_sigmoid(iv), sf = fast_sigmoid(fv);
        const float tg = fast_tanh(gv),   so = fast_sigmoid(ov);
        const float cn = sf * cst[j] + si * tg;
        const float mn = so * fast_tanh(cn);
        const float m2 = mn + p * (mst[j] - mn);
        const float c2 = cn + p * (cst[j] - cn);
        cst[j] = c2; mst[j] = m2;
        m2a[j] = m2; mwp.s[j] = f2bf(m2);
      }
      float* orow = out + (size_t)t * 16384 + (size_t)srow * 512 + hbase;
      *(float4*)(orow + 0) = make_float4(m2a[0], m2a[1], m2a[2], m2a[3]);
      *(float4*)(orow + 4) = make_float4(m2a[4], m2a[5], m2a[6], m2a[7]);
      *(uint4*)((char*)mw + mwoff) = mwp.u;
    }

    // inter-WG barrier (monotonic counter), agent-scope visibility
    __builtin_amdgcn_fence(__ATOMIC_RELEASE, "agent");
    __syncthreads();
    if (tid == 0) {
      __hip_atomic_fetch_add(ctr, 1u, __ATOMIC_RELEASE, __HIP_MEMORY_SCOPE_AGENT);
      const unsigned target = 32u * (unsigned)(t + 1);
      while (__hip_atomic_load(ctr, __ATOMIC_ACQUIRE, __HIP_MEMORY_SCOPE_AGENT) < target)
        __builtin_amdgcn_s_sleep(1);
    }
    __syncthreads();
    __builtin_amdgcn_fence(__ATOMIC_ACQUIRE, "agent");
  }

  // final (m_f, c_f)
  if (tid < 64) {
    float* mo = out + 33554432 + (size_t)srow * 512 + hbase;
    float* co = mo + 16384;
    *(float4*)(mo + 0) = make_float4(mst[0], mst[1], mst[2], mst[3]);
    *(float4*)(mo + 4) = make_float4(mst[4], mst[5], mst[6], mst[7]);
    *(float4*)(co + 0) = make_float4(cst[0], cst[1], cst[2], cst[3]);
    *(float4*)(co + 4) = make_float4(cst[4], cst[5], cst[6], cst[7]);
  }
}

// ---------------------------------------------------------------------------
// Workspace layout (bytes):
//   xp   @ 0          : 65536*2048*2 = 268435456
//   WxT  @ 268435456  : 2097152
//   WhT  @ 270532608  : 2097152
//   mb0  @ 272629760  : 32768
//   mb1  @ 272662528  : 32768
//   ctr  @ 272695296  : 64
// ---------------------------------------------------------------------------
extern "C" void kernel_launch(void* const* d_in, const int* in_sizes, int n_in,
                              void* d_out, int out_size, void* d_ws, size_t ws_size,
                              hipStream_t stream) {
  (void)in_sizes; (void)n_in; (void)out_size; (void)ws_size;
  const float* input = (const float*)d_in[0];
  const float* pads  = (const float*)d_in[1];
  const float* Wx    = (const float*)d_in[2];
  const float* Wh    = (const float*)d_in[3];
  const float* bias  = (const float*)d_in[4];
  float* out = (float*)d_out;

  char* ws = (char*)d_ws;
  unsigned short* xp  = (unsigned short*)(ws);
  unsigned short* WxT = (unsigned short*)(ws + 268435456);
  unsigned short* WhT = (unsigned short*)(ws + 270532608);
  unsigned short* mb0 = (unsigned short*)(ws + 272629760);
  unsigned short* mb1 = (unsigned short*)(ws + 272662528);
  unsigned int*   ctr = (unsigned int*)(ws + 272695296);

  // zero m double-buffer + barrier counter (ws is poisoned 0xAA before each call)
  hipMemsetAsync(ws + 272629760, 0, 32768 * 2 + 64, stream);

  transpose_cvt<<<dim3(64, 16, 2), 256, 0, stream>>>(Wx, Wh, WxT, WhT);
  gemm_xproj<<<dim3(512, 16), 256, 0, stream>>>(input, WxT, bias, xp);
  lstm_rec<<<32, 256, 0, stream>>>(xp, pads, WhT, out, mb0, mb1, ctr);
}

// Round 2
// 7200.597 us; speedup vs baseline: 2.5189x; 2.5189x over previous
//
#include <hip/hip_runtime.h>

// ---------------------------------------------------------------------------
// LSTM recurrence, T=2048, B=32, D=H=512.
//   Phase 1: xp = input @ W_x + b   (bf16 MFMA GEMM) -> ws (bf16)
//   Phase 2: persistent 32-WG recurrence. W_h register-resident as MFMA
//            B-fragments; m double-buffered in global memory in MFMA
//            A-fragment layout, exchanged via RELAXED+AGENT (sc1) accesses —
//            NO fences (avoids per-step buffer_wbl2/buffer_inv L2 flushes).
//            Barrier: 32 per-WG slot words + ballot-poll by wave 0.
// ---------------------------------------------------------------------------

typedef __bf16  bf16x8 __attribute__((ext_vector_type(8)));
typedef float   f32x4  __attribute__((ext_vector_type(4)));

__device__ __forceinline__ unsigned short f2bf(float f) {
  unsigned u = __builtin_bit_cast(unsigned, f);
  u += 0x7fffu + ((u >> 16) & 1u);   // round-to-nearest-even
  return (unsigned short)(u >> 16);
}
__device__ __forceinline__ float bf2f(unsigned short h) {
  unsigned u = ((unsigned)h) << 16;
  return __builtin_bit_cast(float, u);
}
__device__ __forceinline__ float fast_sigmoid(float x) {
  return __builtin_amdgcn_rcpf(1.0f + __expf(-x));
}
__device__ __forceinline__ float fast_tanh(float x) {
  return 2.0f * __builtin_amdgcn_rcpf(1.0f + __expf(-2.0f * x)) - 1.0f;
}

// ---------------------------------------------------------------------------
// Transpose + fp32->bf16 convert: W [512][2048] -> WT [2048][512] bf16.
// ---------------------------------------------------------------------------
__global__ __launch_bounds__(256) void transpose_cvt(
    const float* __restrict__ Wx, const float* __restrict__ Wh,
    unsigned short* __restrict__ WxT, unsigned short* __restrict__ WhT) {
  const float* src = blockIdx.z ? Wh : Wx;
  unsigned short* dst = blockIdx.z ? WhT : WxT;
  __shared__ float tile[32][33];
  const int n0 = blockIdx.x * 32, k0 = blockIdx.y * 32;
  const int t = threadIdx.x;
  {
    const int kk = t >> 3, nn = (t & 7) * 4;
    float4 v = *(const float4*)(src + (size_t)(k0 + kk) * 2048 + n0 + nn);
    tile[kk][nn + 0] = v.x; tile[kk][nn + 1] = v.y;
    tile[kk][nn + 2] = v.z; tile[kk][nn + 3] = v.w;
  }
  __syncthreads();
  {
    const int n = t >> 3, k4 = (t & 7) * 4;
    ushort4 o;
    o.x = f2bf(tile[k4 + 0][n]); o.y = f2bf(tile[k4 + 1][n]);
    o.z = f2bf(tile[k4 + 2][n]); o.w = f2bf(tile[k4 + 3][n]);
    *(ushort4*)(dst + (size_t)(n0 + n) * 512 + k0 + k4) = o;
  }
}

// ---------------------------------------------------------------------------
// xp = input @ W_x + b, output bf16 [65536][2048]. 128x128 tile, 4 waves.
// ---------------------------------------------------------------------------
__global__ __launch_bounds__(256) void gemm_xproj(
    const float* __restrict__ A, const unsigned short* __restrict__ BT,
    const float* __restrict__ bias, unsigned short* __restrict__ C) {
  __shared__ unsigned short As[128 * 32];
  __shared__ unsigned short Bs[128 * 32];
  const int m0 = blockIdx.x * 128, n0 = blockIdx.y * 128;
  const int tid = threadIdx.x, w = tid >> 6, lane = tid & 63;
  const int q = lane >> 4, r = lane & 15;
  const int wm = (w >> 1) * 64, wn = (w & 1) * 64;
  const int srow = tid >> 1, shalf = tid & 1;

  f32x4 acc[4][4] = {};

  for (int kt = 0; kt < 16; ++kt) {
    const int k0 = kt * 32;
    {
      const float* ap = A + (size_t)(m0 + srow) * 512 + k0 + shalf * 16;
#pragma unroll
      for (int c = 0; c < 4; ++c) {
        float4 v = *(const float4*)(ap + c * 4);
        ushort4 h;
        h.x = f2bf(v.x); h.y = f2bf(v.y); h.z = f2bf(v.z); h.w = f2bf(v.w);
        *(ushort4*)&As[srow * 32 + shalf * 16 + c * 4] = h;
      }
    }
    {
      const unsigned short* bp = BT + (size_t)(n0 + srow) * 512 + k0 + shalf * 16;
#pragma unroll
      for (int c2 = 0; c2 < 2; ++c2)
        *(uint4*)&Bs[srow * 32 + shalf * 16 + c2 * 8] = *(const uint4*)(bp + c2 * 8);
    }
    __syncthreads();
    bf16x8 af[4], bfr[4];
#pragma unroll
    for (int i = 0; i < 4; ++i)
      af[i] = *(const bf16x8*)&As[(wm + i * 16 + r) * 32 + q * 8];
#pragma unroll
    for (int j = 0; j < 4; ++j)
      bfr[j] = *(const bf16x8*)&Bs[(wn + j * 16 + r) * 32 + q * 8];
#pragma unroll
    for (int i = 0; i < 4; ++i)
#pragma unroll
      for (int j = 0; j < 4; ++j)
        acc[i][j] = __builtin_amdgcn_mfma_f32_16x16x32_bf16(af[i], bfr[j], acc[i][j], 0, 0, 0);
    __syncthreads();
  }
#pragma unroll
  for (int j = 0; j < 4; ++j) {
    const int col = n0 + wn + j * 16 + r;
    const float bv = bias[col];
#pragma unroll
    for (int i = 0; i < 4; ++i) {
#pragma unroll
      for (int e = 0; e < 4; ++e) {
        const int row = m0 + wm + i * 16 + q * 4 + e;
        C[(size_t)row * 2048 + col] = f2bf(acc[i][j][e] + bv);
      }
    }
  }
}

// ---------------------------------------------------------------------------
// Persistent recurrence: 32 WGs x 256 threads. WG g owns h in [g*16,(g+1)*16).
// Wave w owns n_loc = w*16+r -> h_loc = n_loc>>2 in [w*4,w*4+4), typ = n_loc&3.
// m buffers in MFMA-A-fragment swizzle: element (row,k) at byte
//   ((k>>5)*2 + (row>>4))*1024 + (((k>>3)&3)*16 + (row&15))*16 + (k&7)*2
// Elementwise: lane L of wave w handles cells (row=L>>1, h=g*16+w*4+(L&1)*2 +{0,1}).
// ---------------------------------------------------------------------------
__global__ __launch_bounds__(256, 1) void lstm_rec(
    const unsigned short* __restrict__ xp,   // [65536][2048] bf16
    const float* __restrict__ pads,          // [2048*32]
    const unsigned short* __restrict__ WhT,  // [2048][512] bf16
    float* __restrict__ out,                 // [T*B*H + 2*B*H] fp32
    unsigned short* __restrict__ mb0, unsigned short* __restrict__ mb1,
    unsigned int* __restrict__ slots) {      // 32 slots, 64B stride
  const int g = blockIdx.x, tid = threadIdx.x;
  const int w = tid >> 6, lane = tid & 63, q = lane >> 4, r = lane & 15;

  __shared__ unsigned mA[8192];      // 32 KB, A-fragment-swizzled m copy
  __shared__ float gsm[64 * 33];     // [n_loc][row], stride 33 (per-wave private)

  // ---- register-resident W_h B-fragments ----
  const int n_loc = w * 16 + r;
  const int h_loc = n_loc >> 2, typ = n_loc & 3;
  const int n_glob = typ * 512 + g * 16 + h_loc;
  bf16x8 bfrag[16];
#pragma unroll
  for (int kt = 0; kt < 16; ++kt)
    bfrag[kt] = *(const bf16x8*)(WhT + (size_t)n_glob * 512 + kt * 32 + q * 8);

  // ---- elementwise ownership: 2 cells per lane ----
  const int row = lane >> 1;
  const int hglob = g * 16 + w * 4 + (lane & 1) * 2;    // even
  const size_t mwoff = (size_t)((hglob >> 5) * 2 + (row >> 4)) * 1024 +
                       (size_t)(((hglob >> 3) & 3) * 16 + (row & 15)) * 16 +
                       (size_t)(hglob & 7) * 2;
  float cst0 = 0.f, cst1 = 0.f, mst0 = 0.f, mst1 = 0.f;

  // prefetch xp/pads for t=0
  float pf_p = pads[row];
  unsigned pf_x[4];
#pragma unroll
  for (int ty = 0; ty < 4; ++ty)
    pf_x[ty] = *(const unsigned*)(xp + (size_t)row * 2048 + ty * 512 + hglob);

  for (int t = 0; t < 2048; ++t) {
    const unsigned* mr = (const unsigned*)((t & 1) ? mb1 : mb0);
    unsigned* mw = (unsigned*)((t & 1) ? mb0 : mb1);

    // ---- stage m into LDS (flat copy, device-coherent dword loads) ----
    unsigned mt[32];
#pragma unroll
    for (int i = 0; i < 32; ++i)
      mt[i] = __hip_atomic_load(mr + i * 256 + tid, __ATOMIC_RELAXED,
                                __HIP_MEMORY_SCOPE_AGENT);
#pragma unroll
    for (int i = 0; i < 32; ++i)
      mA[i * 256 + tid] = mt[i];
    __syncthreads();

    // ---- GEMM: gates(n_loc) = m @ W_h[:, n_glob] ----
    f32x4 acc0 = {}, acc1 = {};
#pragma unroll
    for (int kt = 0; kt < 16; ++kt) {
      bf16x8 a0 = *(const bf16x8*)((const char*)mA + (size_t)(kt * 2 + 0) * 1024 + lane * 16);
      bf16x8 a1 = *(const bf16x8*)((const char*)mA + (size_t)(kt * 2 + 1) * 1024 + lane * 16);
      acc0 = __builtin_amdgcn_mfma_f32_16x16x32_bf16(a0, bfrag[kt], acc0, 0, 0, 0);
      acc1 = __builtin_amdgcn_mfma_f32_16x16x32_bf16(a1, bfrag[kt], acc1, 0, 0, 0);
    }
    // transpose within wave via private LDS columns (no barrier needed)
#pragma unroll
    for (int e = 0; e < 4; ++e) {
      gsm[n_loc * 33 + q * 4 + e]      = acc0[e];
      gsm[n_loc * 33 + 16 + q * 4 + e] = acc1[e];
    }
    const float* gcol = gsm + (size_t)(w * 16 + (lane & 1) * 8) * 33 + row;
    float gt[8];
#pragma unroll
    for (int j = 0; j < 8; ++j) gt[j] = gcol[j * 33];

    // ---- elementwise LSTM cell, 2 cells per lane ----
    {
      const float p = pf_p;
      const float xi0 = bf2f((unsigned short)(pf_x[0] & 0xffff));
      const float xi1 = bf2f((unsigned short)(pf_x[0] >> 16));
      const float xf0 = bf2f((unsigned short)(pf_x[1] & 0xffff));
      const float xf1 = bf2f((unsigned short)(pf_x[1] >> 16));
      const float xg0 = bf2f((unsigned short)(pf_x[2] & 0xffff));
      const float xg1 = bf2f((unsigned short)(pf_x[2] >> 16));
      const float xo0 = bf2f((unsigned short)(pf_x[3] & 0xffff));
      const float xo1 = bf2f((unsigned short)(pf_x[3] >> 16));

      const float si0 = fast_sigmoid(gt[0] + xi0), sf0 = fast_sigmoid(gt[1] + xf0);
      const float tg0 = fast_tanh(gt[2] + xg0),    so0 = fast_sigmoid(gt[3] + xo0);
      const float si1 = fast_sigmoid(gt[4] + xi1), sf1 = fast_sigmoid(gt[5] + xf1);
      const float tg1 = fast_tanh(gt[6] + xg1),    so1 = fast_sigmoid(gt[7] + xo1);

      const float cn0 = sf0 * cst0 + si0 * tg0;
      const float cn1 = sf1 * cst1 + si1 * tg1;
      const float mn0 = so0 * fast_tanh(cn0);
      const float mn1 = so1 * fast_tanh(cn1);
      const float m20 = mn0 + p * (mst0 - mn0), c20 = cn0 + p * (cst0 - cn0);
      const float m21 = mn1 + p * (mst1 - mn1), c21 = cn1 + p * (cst1 - cn1);
      cst0 = c20; mst0 = m20; cst1 = c21; mst1 = m21;

      *(float2*)(out + (size_t)t * 16384 + (size_t)row * 512 + hglob) =
          make_float2(m20, m21);
      const unsigned pack = (unsigned)f2bf(m20) | ((unsigned)f2bf(m21) << 16);
      __hip_atomic_store((unsigned*)((char*)mw + mwoff), pack,
                         __ATOMIC_RELAXED, __HIP_MEMORY_SCOPE_AGENT);
    }

    // ---- prefetch xp/pads for t+1 (hides HBM latency under barrier) ----
    {
      const int tn = (t + 1) & 2047;
      pf_p = pads[tn * 32 + row];
#pragma unroll
      for (int ty = 0; ty < 4; ++ty)
        pf_x[ty] = *(const unsigned*)(xp + (size_t)(tn * 32 + row) * 2048 + ty * 512 + hglob);
    }

    // ---- inter-WG barrier: per-WG slots + ballot poll (no fences) ----
    __threadfence_block();
    __syncthreads();   // all m stores drained (vmcnt) before arrival
    if (tid == 0)
      __hip_atomic_store(slots + g * 16, (unsigned)(t + 1),
                         __ATOMIC_RELAXED, __HIP_MEMORY_SCOPE_AGENT);
    if (tid < 64) {
      const unsigned tgt = (unsigned)(t + 1);
      for (;;) {
        unsigned v = (tid < 32)
            ? __hip_atomic_load(slots + tid * 16, __ATOMIC_RELAXED,
                                __HIP_MEMORY_SCOPE_AGENT)
            : tgt;
        if (__ballot(v < tgt) == 0ull) break;
        __builtin_amdgcn_s_sleep(1);
      }
    }
    __syncthreads();
  }

  // final (m_f, c_f)
  {
    float* mo = out + 33554432 + (size_t)row * 512 + hglob;
    *(float2*)mo = make_float2(mst0, mst1);
    *(float2*)(mo + 16384) = make_float2(cst0, cst1);
  }
}

// ---------------------------------------------------------------------------
// Workspace layout (bytes):
//   xp    @ 0          : 268435456
//   WxT   @ 268435456  : 2097152
//   WhT   @ 270532608  : 2097152
//   mb0   @ 272629760  : 32768
//   mb1   @ 272662528  : 32768
//   slots @ 272695296  : 2048
// ---------------------------------------------------------------------------
extern "C" void kernel_launch(void* const* d_in, const int* in_sizes, int n_in,
                              void* d_out, int out_size, void* d_ws, size_t ws_size,
                              hipStream_t stream) {
  (void)in_sizes; (void)n_in; (void)out_size; (void)ws_size;
  const float* input = (const float*)d_in[0];
  const float* pads  = (const float*)d_in[1];
  const float* Wx    = (const float*)d_in[2];
  const float* Wh    = (const float*)d_in[3];
  const float* bias  = (const float*)d_in[4];
  float* out = (float*)d_out;

  char* ws = (char*)d_ws;
  unsigned short* xp  = (unsigned short*)(ws);
  unsigned short* WxT = (unsigned short*)(ws + 268435456);
  unsigned short* WhT = (unsigned short*)(ws + 270532608);
  unsigned short* mb0 = (unsigned short*)(ws + 272629760);
  unsigned short* mb1 = (unsigned short*)(ws + 272662528);
  unsigned int* slots = (unsigned int*)(ws + 272695296);

  hipMemsetAsync(ws + 272629760, 0, 32768 * 2 + 2048, stream);

  transpose_cvt<<<dim3(64, 16, 2), 256, 0, stream>>>(Wx, Wh, WxT, WhT);
  gemm_xproj<<<dim3(512, 16), 256, 0, stream>>>(input, WxT, bias, xp);
  lstm_rec<<<32, 256, 0, stream>>>(xp, pads, WhT, out, mb0, mb1, slots);
}